// Round 1
// baseline (1003.570 us; speedup 1.0000x reference)
//
#include <hip/hip_runtime.h>
#include <math.h>

// Problem constants (fixed by setup_inputs)
#define N_  16
#define C_  512
#define S_  4096          // H*W = 64*64
#define K_  64
#define NS_ (N_ * S_)     // 65536 pixels
#define SCHUNKS 4         // s-split for K3 partials

// ---------------------------------------------------------------------------
// K1: rnorm[p] = 1 / max(||x[n,:,s]||, 1e-12)
// ---------------------------------------------------------------------------
__global__ __launch_bounds__(256) void k_rnorm(const float* __restrict__ x,
                                               float* __restrict__ rnorm) {
    int p = blockIdx.x * 256 + threadIdx.x;      // 0..NS_-1
    int n = p >> 12;                              // S_=4096
    int s = p & (S_ - 1);
    const float* xp = x + (size_t)n * C_ * S_ + s;
    float acc = 0.0f;
#pragma unroll 8
    for (int c = 0; c < C_; ++c) {
        float v = xp[(size_t)c * S_];
        acc = fmaf(v, v, acc);
    }
    rnorm[p] = 1.0f / fmaxf(sqrtf(acc), 1e-12f);
}

// ---------------------------------------------------------------------------
// K2: logits = conv_w @ xn, softmax over k, store a [N][S][K], suma[n][k] atomically
// One thread per pixel; 64 fp32 accumulators in VGPRs; conv_w via uniform
// (scalar) loads -> inner loop is pure v_fmac with SGPR operand.
// ---------------------------------------------------------------------------
__global__ __launch_bounds__(256) void k_assign(const float* __restrict__ x,
                                                const float* __restrict__ conv_w,
                                                const float* __restrict__ rnorm,
                                                float* __restrict__ a_out,
                                                float* __restrict__ suma) {
    int p = blockIdx.x * 256 + threadIdx.x;
    int n = p >> 12;
    int s = p & (S_ - 1);
    const float* xp = x + (size_t)n * C_ * S_ + s;
    float rn = rnorm[p];

    float acc[K_];
#pragma unroll
    for (int k = 0; k < K_; ++k) acc[k] = 0.0f;

    for (int c0 = 0; c0 < C_; c0 += 8) {
        float xv[8];
#pragma unroll
        for (int i = 0; i < 8; ++i) xv[i] = xp[(size_t)(c0 + i) * S_] * rn;
#pragma unroll
        for (int k = 0; k < K_; ++k) {
            const float* wr = conv_w + k * C_ + c0;   // wave-uniform address
#pragma unroll
            for (int i = 0; i < 8; ++i) acc[k] = fmaf(wr[i], xv[i], acc[k]);
        }
    }

    // softmax over the 64 registers
    float m = acc[0];
#pragma unroll
    for (int k = 1; k < K_; ++k) m = fmaxf(m, acc[k]);
    float sum = 0.0f;
#pragma unroll
    for (int k = 0; k < K_; ++k) { acc[k] = __expf(acc[k] - m); sum += acc[k]; }
    float inv = 1.0f / sum;
#pragma unroll
    for (int k = 0; k < K_; ++k) acc[k] *= inv;

    // store a as [N][S][K] (row of 64 contiguous per pixel)
    float4* ap = (float4*)(a_out + (size_t)p * K_);
#pragma unroll
    for (int q = 0; q < K_ / 4; ++q)
        ap[q] = make_float4(acc[4 * q], acc[4 * q + 1], acc[4 * q + 2], acc[4 * q + 3]);

    // suma[n][k]: wave-reduce each k, lane k keeps the wave total, one atomic/lane
    int lane = threadIdx.x & 63;
    float mine = 0.0f;
#pragma unroll
    for (int k = 0; k < K_; ++k) {
        float v = acc[k];
#pragma unroll
        for (int off = 32; off > 0; off >>= 1) v += __shfl_xor(v, off);
        mine = (lane == k) ? v : mine;
    }
    atomicAdd(&suma[n * K_ + lane], mine);
}

// ---------------------------------------------------------------------------
// K3: partial[sc][n][k][c] = sum_{s in chunk} a[n,s,k] * x[n,c,s]*rnorm
// LDS-tiled GEMM: 64k x 64c tile per block, 32-s steps, X transposed in LDS.
// grid = (ct=8, sc=4, n=16), 256 threads; thread owns 4k x 4c accumulators.
// ---------------------------------------------------------------------------
__global__ __launch_bounds__(256) void k_agg(const float* __restrict__ x,
                                             const float* __restrict__ rnorm,
                                             const float* __restrict__ a_in,
                                             float* __restrict__ partial) {
    int ct = blockIdx.x;   // c-tile of 64
    int sc = blockIdx.y;   // s-chunk of 1024
    int n  = blockIdx.z;

    __shared__ float A[32][K_];   // a[s][k]
    __shared__ float X[32][64];   // xn[s][c_local] (transposed)

    int t  = threadIdx.x;
    int kk = t & 15;              // k = kk*4 .. +3
    int cg = t >> 4;              // c_local = cg*4 .. +3

    float acc[4][4];
#pragma unroll
    for (int i = 0; i < 4; ++i)
#pragma unroll
        for (int j = 0; j < 4; ++j) acc[i][j] = 0.0f;

    const int SCH = S_ / SCHUNKS;  // 1024
    const float* abase = a_in + ((size_t)n * S_ + (size_t)sc * SCH) * K_;
    const float* xbase = x + (size_t)n * C_ * S_ + (size_t)(ct * 64) * S_ + (size_t)sc * SCH;
    const float* rbase = rnorm + n * S_ + sc * SCH;

    for (int s0 = 0; s0 < SCH; s0 += 32) {
        // stage A tile: 32 rows x 64 floats, contiguous
        {
            int r   = t >> 3;           // 0..31
            int col = (t & 7) * 8;      // 0..56
            const float4* src = (const float4*)(abase + (size_t)(s0 + r) * K_ + col);
            *(float4*)&A[r][col]     = src[0];
            *(float4*)&A[r][col + 4] = src[1];
        }
        // stage X transposed: read x rows (contiguous), write X[s][c_local]
        {
            int cl = t >> 3;            // 0..31
            int so = (t & 7) * 4;       // 0..28
#pragma unroll
            for (int h = 0; h < 2; ++h) {
                int c_l = cl + h * 32;
                float4 v = *(const float4*)(xbase + (size_t)c_l * S_ + s0 + so);
                float4 r = *(const float4*)(rbase + s0 + so);
                X[so + 0][c_l] = v.x * r.x;
                X[so + 1][c_l] = v.y * r.y;
                X[so + 2][c_l] = v.z * r.z;
                X[so + 3][c_l] = v.w * r.w;
            }
        }
        __syncthreads();
#pragma unroll
        for (int ss = 0; ss < 32; ++ss) {
            float4 av = *(const float4*)&A[ss][kk * 4];
            float4 xv = *(const float4*)&X[ss][cg * 4];
            float aa[4] = {av.x, av.y, av.z, av.w};
            float xx[4] = {xv.x, xv.y, xv.z, xv.w};
#pragma unroll
            for (int i = 0; i < 4; ++i)
#pragma unroll
                for (int j = 0; j < 4; ++j)
                    acc[i][j] = fmaf(aa[i], xx[j], acc[i][j]);
        }
        __syncthreads();
    }

    // write partial[sc][n][k][ct*64 + c]
    float* pb = partial + (((size_t)sc * N_ + n) * K_) * C_ + (size_t)ct * 64;
#pragma unroll
    for (int i = 0; i < 4; ++i) {
        *(float4*)&pb[(size_t)(kk * 4 + i) * C_ + cg * 4] =
            make_float4(acc[i][0], acc[i][1], acc[i][2], acc[i][3]);
    }
}

// ---------------------------------------------------------------------------
// K4: vlad[n,k,c] = sum_sc partial[sc][n][k][c] - centroids[k][c]*suma[n][k]
// ---------------------------------------------------------------------------
__global__ __launch_bounds__(256) void k_final(const float* __restrict__ partial,
                                               const float* __restrict__ suma,
                                               const float* __restrict__ centroids,
                                               float* __restrict__ out) {
    int idx = blockIdx.x * 256 + threadIdx.x;       // over N*K*C/4 float4s
    int c4 = idx & (C_ / 4 - 1);                    // 0..127
    int k  = (idx >> 7) & (K_ - 1);
    int n  = idx >> 13;
    size_t off = (((size_t)n * K_) + k) * C_ + (size_t)c4 * 4;

    float4 acc = make_float4(0.f, 0.f, 0.f, 0.f);
#pragma unroll
    for (int ch = 0; ch < SCHUNKS; ++ch) {
        float4 v = *(const float4*)(partial + (size_t)ch * N_ * K_ * C_ + off);
        acc.x += v.x; acc.y += v.y; acc.z += v.z; acc.w += v.w;
    }
    float sm = suma[n * K_ + k];
    float4 cen = *(const float4*)(centroids + (size_t)k * C_ + c4 * 4);
    float4 r = make_float4(acc.x - cen.x * sm, acc.y - cen.y * sm,
                           acc.z - cen.z * sm, acc.w - cen.w * sm);
    *(float4*)(out + off) = r;
}

// ---------------------------------------------------------------------------
extern "C" void kernel_launch(void* const* d_in, const int* in_sizes, int n_in,
                              void* d_out, int out_size, void* d_ws, size_t ws_size,
                              hipStream_t stream) {
    const float* x         = (const float*)d_in[0];
    const float* conv_w    = (const float*)d_in[1];
    const float* centroids = (const float*)d_in[2];
    float* out = (float*)d_out;

    // workspace layout (floats)
    float* ws      = (float*)d_ws;
    float* rnorm   = ws;                               // NS_
    float* a       = rnorm + NS_;                      // NS_*K_
    float* suma    = a + (size_t)NS_ * K_;             // N_*K_
    float* partial = suma + N_ * K_;                   // SCHUNKS*N_*K_*C_

    hipMemsetAsync(suma, 0, N_ * K_ * sizeof(float), stream);

    k_rnorm <<<NS_ / 256, 256, 0, stream>>>(x, rnorm);
    k_assign<<<NS_ / 256, 256, 0, stream>>>(x, conv_w, rnorm, a, suma);
    k_agg   <<<dim3(C_ / 64, SCHUNKS, N_), 256, 0, stream>>>(x, rnorm, a, partial);
    k_final <<<(N_ * K_ * C_ / 4) / 256, 256, 0, stream>>>(partial, suma, centroids, out);
}

// Round 2
// 564.807 us; speedup vs baseline: 1.7768x; 1.7768x over previous
//
#include <hip/hip_runtime.h>
#include <math.h>

// Problem constants (fixed by setup_inputs)
#define N_  16
#define C_  512
#define S_  4096          // H*W = 64*64
#define K_  64
#define NS_ (N_ * S_)     // 65536 pixels
#define SCHUNKS 4         // s-split for K3 partials

// ---------------------------------------------------------------------------
// K1: rnorm[p] = 1 / max(||x[n,:,s]||, 1e-12)
// Block = 64 consecutive s of one n; 256 threads = 16 c-groups x 16 s-quads.
// All loads are coalesced float4 along s.
// ---------------------------------------------------------------------------
__global__ __launch_bounds__(256) void k_rnorm(const float* __restrict__ x,
                                               float* __restrict__ rnorm) {
    int b  = blockIdx.x;              // 0..1023
    int n  = b >> 6;                  // 64 blocks per n
    int s0 = (b & 63) * 64;
    int t  = threadIdx.x;
    int s4 = t & 15;                  // which float4 within the 64 s
    int cg = t >> 4;                  // c-group 0..15
    const float* xp = x + (size_t)n * C_ * S_ + s0 + s4 * 4;

    float4 acc = make_float4(0.f, 0.f, 0.f, 0.f);
    for (int c = cg; c < C_; c += 16) {
        float4 v = *(const float4*)(xp + (size_t)c * S_);
        acc.x = fmaf(v.x, v.x, acc.x);
        acc.y = fmaf(v.y, v.y, acc.y);
        acc.z = fmaf(v.z, v.z, acc.z);
        acc.w = fmaf(v.w, v.w, acc.w);
    }
    __shared__ float4 red[16][16];    // [cg][s4]
    red[cg][s4] = acc;
    __syncthreads();
    if (t < 16) {
        float4 sum = red[0][t];
#pragma unroll
        for (int g = 1; g < 16; ++g) {
            float4 v = red[g][t];
            sum.x += v.x; sum.y += v.y; sum.z += v.z; sum.w += v.w;
        }
        float4 r;
        r.x = 1.0f / fmaxf(sqrtf(sum.x), 1e-12f);
        r.y = 1.0f / fmaxf(sqrtf(sum.y), 1e-12f);
        r.z = 1.0f / fmaxf(sqrtf(sum.z), 1e-12f);
        r.w = 1.0f / fmaxf(sqrtf(sum.w), 1e-12f);
        *(float4*)(rnorm + n * S_ + s0 + t * 4) = r;
    }
}

// ---------------------------------------------------------------------------
// K2: logits = conv_w @ xn, softmax over k, a -> [N][S][K], suma atomically.
// Block = 128 pixels. Threads 0..127 compute k 0..31; threads 128..255
// compute k 32..63 (km is wave-uniform; readfirstlane keeps conv_w on the
// scalar-load path). 32 accumulators/thread -> no spills.
// ---------------------------------------------------------------------------
__global__ __launch_bounds__(256, 2) void k_assign(const float* __restrict__ x,
                                                   const float* __restrict__ conv_w,
                                                   const float* __restrict__ rnorm,
                                                   float* __restrict__ a_out,
                                                   float* __restrict__ suma) {
    int tid = threadIdx.x;
    int km  = __builtin_amdgcn_readfirstlane(tid >> 7);   // 0 or 1, wave-uniform
    int pl  = tid & 127;
    int p   = blockIdx.x * 128 + pl;
    int n   = p >> 12;
    int s   = p & (S_ - 1);
    const float* xp    = x + (size_t)n * C_ * S_ + s;
    const float* wbase = conv_w + (size_t)km * 32 * C_;
    float rn = rnorm[p];

    float acc[32];
#pragma unroll
    for (int k = 0; k < 32; ++k) acc[k] = 0.0f;

    for (int c0 = 0; c0 < C_; c0 += 8) {
        float xv[8];
#pragma unroll
        for (int i = 0; i < 8; ++i) xv[i] = xp[(size_t)(c0 + i) * S_] * rn;
#pragma unroll
        for (int k = 0; k < 32; ++k) {
            const float* wr = wbase + k * C_ + c0;        // wave-uniform
#pragma unroll
            for (int i = 0; i < 8; ++i) acc[k] = fmaf(wr[i], xv[i], acc[k]);
        }
    }

    // cross-half softmax (max then sum) via LDS
    __shared__ float red[2][128];
    float m = acc[0];
#pragma unroll
    for (int k = 1; k < 32; ++k) m = fmaxf(m, acc[k]);
    red[km][pl] = m;
    __syncthreads();
    m = fmaxf(red[0][pl], red[1][pl]);

    float lsum = 0.0f;
#pragma unroll
    for (int k = 0; k < 32; ++k) { acc[k] = __expf(acc[k] - m); lsum += acc[k]; }
    __syncthreads();                      // red reuse
    red[km][pl] = lsum;
    __syncthreads();
    float inv = 1.0f / (red[0][pl] + red[1][pl]);
#pragma unroll
    for (int k = 0; k < 32; ++k) acc[k] *= inv;

    // store a[p][km*32 .. +31]
    float4* ap = (float4*)(a_out + (size_t)p * K_ + km * 32);
#pragma unroll
    for (int q = 0; q < 8; ++q)
        ap[q] = make_float4(acc[4 * q], acc[4 * q + 1], acc[4 * q + 2], acc[4 * q + 3]);

    // suma[n][km*32 + k]: butterfly-reduce each k across the wave, lane k keeps it
    int lane = tid & 63;
    float mine = 0.0f;
#pragma unroll
    for (int k = 0; k < 32; ++k) {
        float v = acc[k];
#pragma unroll
        for (int off = 32; off > 0; off >>= 1) v += __shfl_xor(v, off);
        if (lane == k) mine = v;
    }
    if (lane < 32) atomicAdd(&suma[n * K_ + km * 32 + lane], mine);
}

// ---------------------------------------------------------------------------
// K3: partial[sc][n][k][c] = sum_{s in chunk} a[n,s,k] * x[n,c,s]*rnorm
// (unchanged from round 0)
// ---------------------------------------------------------------------------
__global__ __launch_bounds__(256) void k_agg(const float* __restrict__ x,
                                             const float* __restrict__ rnorm,
                                             const float* __restrict__ a_in,
                                             float* __restrict__ partial) {
    int ct = blockIdx.x;   // c-tile of 64
    int sc = blockIdx.y;   // s-chunk of 1024
    int n  = blockIdx.z;

    __shared__ float A[32][K_];   // a[s][k]
    __shared__ float X[32][64];   // xn[s][c_local]

    int t  = threadIdx.x;
    int kk = t & 15;
    int cg = t >> 4;

    float acc[4][4];
#pragma unroll
    for (int i = 0; i < 4; ++i)
#pragma unroll
        for (int j = 0; j < 4; ++j) acc[i][j] = 0.0f;

    const int SCH = S_ / SCHUNKS;
    const float* abase = a_in + ((size_t)n * S_ + (size_t)sc * SCH) * K_;
    const float* xbase = x + (size_t)n * C_ * S_ + (size_t)(ct * 64) * S_ + (size_t)sc * SCH;
    const float* rbase = rnorm + n * S_ + sc * SCH;

    for (int s0 = 0; s0 < SCH; s0 += 32) {
        {
            int r   = t >> 3;
            int col = (t & 7) * 8;
            const float4* src = (const float4*)(abase + (size_t)(s0 + r) * K_ + col);
            *(float4*)&A[r][col]     = src[0];
            *(float4*)&A[r][col + 4] = src[1];
        }
        {
            int cl = t >> 3;
            int so = (t & 7) * 4;
#pragma unroll
            for (int h = 0; h < 2; ++h) {
                int c_l = cl + h * 32;
                float4 v = *(const float4*)(xbase + (size_t)c_l * S_ + s0 + so);
                float4 r = *(const float4*)(rbase + s0 + so);
                X[so + 0][c_l] = v.x * r.x;
                X[so + 1][c_l] = v.y * r.y;
                X[so + 2][c_l] = v.z * r.z;
                X[so + 3][c_l] = v.w * r.w;
            }
        }
        __syncthreads();
#pragma unroll
        for (int ss = 0; ss < 32; ++ss) {
            float4 av = *(const float4*)&A[ss][kk * 4];
            float4 xv = *(const float4*)&X[ss][cg * 4];
            float aa[4] = {av.x, av.y, av.z, av.w};
            float xx[4] = {xv.x, xv.y, xv.z, xv.w};
#pragma unroll
            for (int i = 0; i < 4; ++i)
#pragma unroll
                for (int j = 0; j < 4; ++j)
                    acc[i][j] = fmaf(aa[i], xx[j], acc[i][j]);
        }
        __syncthreads();
    }

    float* pb = partial + (((size_t)sc * N_ + n) * K_) * C_ + (size_t)ct * 64;
#pragma unroll
    for (int i = 0; i < 4; ++i) {
        *(float4*)&pb[(size_t)(kk * 4 + i) * C_ + cg * 4] =
            make_float4(acc[i][0], acc[i][1], acc[i][2], acc[i][3]);
    }
}

// ---------------------------------------------------------------------------
// K4: vlad[n,k,c] = sum_sc partial[sc][n][k][c] - centroids[k][c]*suma[n][k]
// ---------------------------------------------------------------------------
__global__ __launch_bounds__(256) void k_final(const float* __restrict__ partial,
                                               const float* __restrict__ suma,
                                               const float* __restrict__ centroids,
                                               float* __restrict__ out) {
    int idx = blockIdx.x * 256 + threadIdx.x;
    int c4 = idx & (C_ / 4 - 1);
    int k  = (idx >> 7) & (K_ - 1);
    int n  = idx >> 13;
    size_t off = (((size_t)n * K_) + k) * C_ + (size_t)c4 * 4;

    float4 acc = make_float4(0.f, 0.f, 0.f, 0.f);
#pragma unroll
    for (int ch = 0; ch < SCHUNKS; ++ch) {
        float4 v = *(const float4*)(partial + (size_t)ch * N_ * K_ * C_ + off);
        acc.x += v.x; acc.y += v.y; acc.z += v.z; acc.w += v.w;
    }
    float sm = suma[n * K_ + k];
    float4 cen = *(const float4*)(centroids + (size_t)k * C_ + c4 * 4);
    float4 r = make_float4(acc.x - cen.x * sm, acc.y - cen.y * sm,
                           acc.z - cen.z * sm, acc.w - cen.w * sm);
    *(float4*)(out + off) = r;
}

// ---------------------------------------------------------------------------
extern "C" void kernel_launch(void* const* d_in, const int* in_sizes, int n_in,
                              void* d_out, int out_size, void* d_ws, size_t ws_size,
                              hipStream_t stream) {
    const float* x         = (const float*)d_in[0];
    const float* conv_w    = (const float*)d_in[1];
    const float* centroids = (const float*)d_in[2];
    float* out = (float*)d_out;

    float* ws      = (float*)d_ws;
    float* rnorm   = ws;                               // NS_
    float* a       = rnorm + NS_;                      // NS_*K_
    float* suma    = a + (size_t)NS_ * K_;             // N_*K_
    float* partial = suma + N_ * K_;                   // SCHUNKS*N_*K_*C_

    hipMemsetAsync(suma, 0, N_ * K_ * sizeof(float), stream);

    k_rnorm <<<NS_ / 64, 256, 0, stream>>>(x, rnorm);
    k_assign<<<NS_ / 128, 256, 0, stream>>>(x, conv_w, rnorm, a, suma);
    k_agg   <<<dim3(C_ / 64, SCHUNKS, N_), 256, 0, stream>>>(x, rnorm, a, partial);
    k_final <<<(N_ * K_ * C_ / 4) / 256, 256, 0, stream>>>(partial, suma, centroids, out);
}

// Round 3
// 256.846 us; speedup vs baseline: 3.9073x; 2.1990x over previous
//
#include <hip/hip_runtime.h>
#include <math.h>

// Problem constants (fixed by setup_inputs)
#define N_  16
#define C_  512
#define S_  4096          // H*W
#define K_  64
#define NS_ (N_ * S_)
#define SC_ 4             // s-chunks in k_agg

typedef float f32x4 __attribute__((ext_vector_type(4)));
typedef short s16x8 __attribute__((ext_vector_type(8)));

__device__ inline unsigned short f2bf(float f) {
    unsigned u = __builtin_bit_cast(unsigned, f);
    return (unsigned short)((u + 0x7FFFu + ((u >> 16) & 1u)) >> 16);   // RNE
}

// ---------------------------------------------------------------------------
// K1: rnorm[p] = 1/max(||x[n,:,s]||,1e-12). (proven in round 1/2)
// ---------------------------------------------------------------------------
__global__ __launch_bounds__(256) void k_rnorm(const float* __restrict__ x,
                                               float* __restrict__ rnorm) {
    int b  = blockIdx.x;
    int n  = b >> 6;
    int s0 = (b & 63) * 64;
    int t  = threadIdx.x;
    int s4 = t & 15;
    int cg = t >> 4;
    const float* xp = x + (size_t)n * C_ * S_ + s0 + s4 * 4;

    float4 acc = make_float4(0.f, 0.f, 0.f, 0.f);
    for (int c = cg; c < C_; c += 16) {
        float4 v = *(const float4*)(xp + (size_t)c * S_);
        acc.x = fmaf(v.x, v.x, acc.x);
        acc.y = fmaf(v.y, v.y, acc.y);
        acc.z = fmaf(v.z, v.z, acc.z);
        acc.w = fmaf(v.w, v.w, acc.w);
    }
    __shared__ float4 red[16][16];
    red[cg][s4] = acc;
    __syncthreads();
    if (t < 16) {
        float4 sum = red[0][t];
#pragma unroll
        for (int g = 1; g < 16; ++g) {
            float4 v = red[g][t];
            sum.x += v.x; sum.y += v.y; sum.z += v.z; sum.w += v.w;
        }
        float4 r;
        r.x = 1.0f / fmaxf(sqrtf(sum.x), 1e-12f);
        r.y = 1.0f / fmaxf(sqrtf(sum.y), 1e-12f);
        r.z = 1.0f / fmaxf(sqrtf(sum.z), 1e-12f);
        r.w = 1.0f / fmaxf(sqrtf(sum.w), 1e-12f);
        *(float4*)(rnorm + n * S_ + s0 + t * 4) = r;
    }
}

// ---------------------------------------------------------------------------
// K1b: conv_w fp32 -> bf16 [K][C]
// ---------------------------------------------------------------------------
__global__ __launch_bounds__(256) void k_wcast(const float* __restrict__ w,
                                               unsigned short* __restrict__ wb) {
    int i = blockIdx.x * 256 + threadIdx.x;    // grid = K_*C_/256
    wb[i] = f2bf(w[i]);
}

// ---------------------------------------------------------------------------
// K2: MFMA logits (u = w_bf @ x_bf), scale by rnorm, softmax over k,
//     store a~ = a*rn as bf16 [N][K][S], suma[n][k] via LDS + atomics.
// Block = (n, 128 s). 4 waves, wave w owns s-subtiles st=2w,2w+1 (16 s each).
// x staged per 32-c step into LDS in EXACT B-fragment layout:
//   Bf[st*512 + g*128 + r*8 + i]  (st=s>>4, r=s&15, g=c_local>>3, i=c_local&7)
// -> consumer ds_read_b128 is linear in lane (conflict-free);
//    staging u32 writes land 2 lanes/bank (free).
// MFMA layout (gfx950 16x16x32_bf16): A[m=lane&15][k=8*(lane>>4)+i],
//   B[k=8*(lane>>4)+i][n=lane&15], D[m=4*(lane>>4)+reg][n=lane&15].
// ---------------------------------------------------------------------------
__global__ __launch_bounds__(256) void k_logits(const float* __restrict__ x,
                                                const unsigned short* __restrict__ wb,
                                                const float* __restrict__ rnorm,
                                                unsigned short* __restrict__ a_out,
                                                float* __restrict__ suma) {
    __shared__ unsigned short Bf[8 * 512];
    __shared__ float suma_l[K_];

    const int s0   = blockIdx.x * 128;
    const int n    = blockIdx.y;
    const int tid  = threadIdx.x;
    const int lane = tid & 63;
    const int w    = tid >> 6;
    const int r    = lane & 15;
    const int g    = lane >> 4;

    // staging role: thread handles c_local = 2*cg, 2*cg+1; s_local = r_t + 16q
    const int r_t = tid & 15;
    const int cg  = tid >> 4;      // 0..15
    const int gw  = cg >> 2;       // destination g
    const int cb  = cg & 3;

    if (tid < K_) suma_l[tid] = 0.0f;

    f32x4 acc[4][2];
#pragma unroll
    for (int mt = 0; mt < 4; ++mt)
#pragma unroll
        for (int st = 0; st < 2; ++st) acc[mt][st] = (f32x4)(0.0f);

    const float* xg = x + ((size_t)n * C_ + 2 * cg) * S_ + s0 + r_t;
    const unsigned short* wg = wb + r * C_ + g * 8;
    unsigned* Bw = (unsigned*)Bf;

    for (int ks = 0; ks < 16; ++ks) {
        // ---- stage 32c x 128s tile (bf16) into frag layout ----
        const float* xk = xg + (size_t)ks * 32 * S_;
#pragma unroll
        for (int q = 0; q < 8; ++q) {
            float v0 = xk[16 * q];
            float v1 = xk[(size_t)S_ + 16 * q];
            unsigned pack = (unsigned)f2bf(v0) | ((unsigned)f2bf(v1) << 16);
            Bw[q * 256 + gw * 64 + r_t * 4 + cb] = pack;
        }
        __syncthreads();
        // ---- MFMA ----
        s16x8 bfr[2];
        bfr[0] = *(const s16x8*)(Bf + (2 * w + 0) * 512 + g * 128 + r * 8);
        bfr[1] = *(const s16x8*)(Bf + (2 * w + 1) * 512 + g * 128 + r * 8);
#pragma unroll
        for (int mt = 0; mt < 4; ++mt) {
            s16x8 af = *(const s16x8*)(wg + (size_t)mt * 16 * C_ + ks * 32);
            acc[mt][0] = __builtin_amdgcn_mfma_f32_16x16x32_bf16(af, bfr[0], acc[mt][0], 0, 0, 0);
            acc[mt][1] = __builtin_amdgcn_mfma_f32_16x16x32_bf16(af, bfr[1], acc[mt][1], 0, 0, 0);
        }
        __syncthreads();
    }

    // ---- normalize logits by rnorm, softmax over the 64 k ----
    const float rn0 = rnorm[n * S_ + s0 + (2 * w + 0) * 16 + r];
    const float rn1 = rnorm[n * S_ + s0 + (2 * w + 1) * 16 + r];

    float lg[2][16];
#pragma unroll
    for (int mt = 0; mt < 4; ++mt)
#pragma unroll
        for (int j = 0; j < 4; ++j) {
            lg[0][mt * 4 + j] = acc[mt][0][j] * rn0;
            lg[1][mt * 4 + j] = acc[mt][1][j] * rn1;
        }

    float av[2][16];
#pragma unroll
    for (int st = 0; st < 2; ++st) {
        float m = lg[st][0];
#pragma unroll
        for (int i = 1; i < 16; ++i) m = fmaxf(m, lg[st][i]);
        m = fmaxf(m, __shfl_xor(m, 16));
        m = fmaxf(m, __shfl_xor(m, 32));
        float s = 0.0f;
#pragma unroll
        for (int i = 0; i < 16; ++i) { av[st][i] = __expf(lg[st][i] - m); s += av[st][i]; }
        s += __shfl_xor(s, 16);
        s += __shfl_xor(s, 32);
        float inv = 1.0f / s;
#pragma unroll
        for (int i = 0; i < 16; ++i) av[st][i] *= inv;
    }

    // ---- suma (unscaled a): reduce over the 16 s-columns per group ----
    float sv[16];
#pragma unroll
    for (int i = 0; i < 16; ++i) sv[i] = av[0][i] + av[1][i];
#pragma unroll
    for (int off = 1; off < 16; off <<= 1)
#pragma unroll
        for (int i = 0; i < 16; ++i) sv[i] += __shfl_xor(sv[i], off);
    if (r == 0) {
#pragma unroll
        for (int mt = 0; mt < 4; ++mt)
#pragma unroll
            for (int j = 0; j < 4; ++j)
                atomicAdd(&suma_l[mt * 16 + 4 * g + j], sv[mt * 4 + j]);
    }
    __syncthreads();
    if (tid < K_) atomicAdd(&suma[n * K_ + tid], suma_l[tid]);

    // ---- store a~ = a * rn  (bf16, [N][K][S]) ----
    unsigned short* ab = a_out + (size_t)n * K_ * S_ + s0 + r;
#pragma unroll
    for (int mt = 0; mt < 4; ++mt)
#pragma unroll
        for (int j = 0; j < 4; ++j) {
            int kc = mt * 16 + 4 * g + j;
            ab[(size_t)kc * S_ + (2 * w + 0) * 16] = f2bf(av[0][mt * 4 + j] * rn0);
            ab[(size_t)kc * S_ + (2 * w + 1) * 16] = f2bf(av[1][mt * 4 + j] * rn1);
        }
}

// ---------------------------------------------------------------------------
// K3: partial[sc][n][k][c] = sum_{s in chunk} a~[k,s] * x_bf[c,s]
// MFMA, no LDS: A-frags from a~ (bf16, s-contig); B-frags from raw x fp32
// with inline bf16 cvt. Block = (ct:128c, sc:1024s, n); wave w owns 32 c.
// ---------------------------------------------------------------------------
__global__ __launch_bounds__(256) void k_agg(const float* __restrict__ x,
                                             const unsigned short* __restrict__ a_in,
                                             float* __restrict__ partial) {
    const int ct   = blockIdx.x;   // 0..3
    const int sc   = blockIdx.y;   // 0..3
    const int n    = blockIdx.z;
    const int tid  = threadIdx.x;
    const int lane = tid & 63;
    const int w    = tid >> 6;
    const int r    = lane & 15;
    const int g    = lane >> 4;

    f32x4 acc[4][2];
#pragma unroll
    for (int mt = 0; mt < 4; ++mt)
#pragma unroll
        for (int nt = 0; nt < 2; ++nt) acc[mt][nt] = (f32x4)(0.0f);

    const unsigned short* ag = a_in + ((size_t)n * K_ + r) * S_ + sc * 1024 + g * 8;
    const float* xg = x + ((size_t)n * C_ + ct * 128 + w * 32 + r) * S_ + sc * 1024 + g * 8;

    for (int ks = 0; ks < 32; ++ks) {
        s16x8 af[4];
#pragma unroll
        for (int mt = 0; mt < 4; ++mt)
            af[mt] = *(const s16x8*)(ag + (size_t)mt * 16 * S_ + ks * 32);
#pragma unroll
        for (int nt = 0; nt < 2; ++nt) {
            const float* xp = xg + (size_t)nt * 16 * S_ + ks * 32;
            float4 f0 = *(const float4*)(xp);
            float4 f1 = *(const float4*)(xp + 4);
            s16x8 bf;
            bf[0] = (short)f2bf(f0.x); bf[1] = (short)f2bf(f0.y);
            bf[2] = (short)f2bf(f0.z); bf[3] = (short)f2bf(f0.w);
            bf[4] = (short)f2bf(f1.x); bf[5] = (short)f2bf(f1.y);
            bf[6] = (short)f2bf(f1.z); bf[7] = (short)f2bf(f1.w);
#pragma unroll
            for (int mt = 0; mt < 4; ++mt)
                acc[mt][nt] = __builtin_amdgcn_mfma_f32_16x16x32_bf16(af[mt], bf, acc[mt][nt], 0, 0, 0);
        }
    }

    float* pb = partial + (((size_t)sc * N_ + n) * K_) * C_ + ct * 128 + w * 32 + r;
#pragma unroll
    for (int mt = 0; mt < 4; ++mt)
#pragma unroll
        for (int nt = 0; nt < 2; ++nt)
#pragma unroll
            for (int j = 0; j < 4; ++j)
                pb[(size_t)(mt * 16 + 4 * g + j) * C_ + nt * 16] = acc[mt][nt][j];
}

// ---------------------------------------------------------------------------
// K4: vlad[n,k,c] = sum_sc partial - centroids[k][c]*suma[n][k]
// ---------------------------------------------------------------------------
__global__ __launch_bounds__(256) void k_final(const float* __restrict__ partial,
                                               const float* __restrict__ suma,
                                               const float* __restrict__ centroids,
                                               float* __restrict__ out) {
    int idx = blockIdx.x * 256 + threadIdx.x;
    int c4 = idx & (C_ / 4 - 1);
    int k  = (idx >> 7) & (K_ - 1);
    int n  = idx >> 13;
    size_t off = (((size_t)n * K_) + k) * C_ + (size_t)c4 * 4;

    float4 acc = make_float4(0.f, 0.f, 0.f, 0.f);
#pragma unroll
    for (int ch = 0; ch < SC_; ++ch) {
        float4 v = *(const float4*)(partial + (size_t)ch * N_ * K_ * C_ + off);
        acc.x += v.x; acc.y += v.y; acc.z += v.z; acc.w += v.w;
    }
    float sm = suma[n * K_ + k];
    float4 cen = *(const float4*)(centroids + (size_t)k * C_ + c4 * 4);
    float4 rr = make_float4(acc.x - cen.x * sm, acc.y - cen.y * sm,
                            acc.z - cen.z * sm, acc.w - cen.w * sm);
    *(float4*)(out + off) = rr;
}

// ---------------------------------------------------------------------------
extern "C" void kernel_launch(void* const* d_in, const int* in_sizes, int n_in,
                              void* d_out, int out_size, void* d_ws, size_t ws_size,
                              hipStream_t stream) {
    const float* x         = (const float*)d_in[0];
    const float* conv_w    = (const float*)d_in[1];
    const float* centroids = (const float*)d_in[2];
    float* out = (float*)d_out;

    // workspace layout (~17.1 MB, under the >=25 MB proven in rounds 1-2)
    float* ws      = (float*)d_ws;
    float* rnorm   = ws;                                   // NS_ f32
    float* suma    = rnorm + NS_;                          // N_*K_ f32
    float* partial = suma + N_ * K_;                       // SC_*N_*K_*C_ f32
    unsigned short* wb = (unsigned short*)(partial + (size_t)SC_ * N_ * K_ * C_); // K_*C_ bf16
    unsigned short* a  = wb + K_ * C_;                     // N_*K_*S_ bf16

    hipMemsetAsync(suma, 0, N_ * K_ * sizeof(float), stream);

    k_rnorm <<<NS_ / 64, 256, 0, stream>>>(x, rnorm);
    k_wcast <<<K_ * C_ / 256, 256, 0, stream>>>(conv_w, wb);
    k_logits<<<dim3(S_ / 128, N_), 256, 0, stream>>>(x, wb, rnorm, a, suma);
    k_agg   <<<dim3(4, SC_, N_), 256, 0, stream>>>(x, a, partial);
    k_final <<<(N_ * K_ * C_ / 4) / 256, 256, 0, stream>>>(partial, suma, centroids, out);
}